// Round 2
// baseline (616.821 us; speedup 1.0000x reference)
//
#include <hip/hip_runtime.h>
#include <cstdint>
#include <cstddef>

// Problem sizes (fixed by the reference)
constexpr int Bb = 64, Ss = 197, Dd = 1024, Hh = 4096;
constexpr int M  = Bb * Ss;            // 12608 tokens
constexpr int MT = (M + 127) / 128;    // 99 M-tiles
constexpr int Mpad = MT * 128;         // 12672 (padded rows)

// scalar slot indices (at base of ws, as u32/f32)
#define SL_MAXW1 0
#define SL_MAXW2 1
#define SL_MAXY  2
#define SL_S1    4
#define SL_BERF  5
#define SL_CERF  6
#define SL_SHIFT 7
#define SL_S2    8
#define SL_SA    9
#define SL_SOUT2 10
#define SL_SW1   11
#define SL_SW2   12

typedef int v4i __attribute__((ext_vector_type(4)));

#define GLD_LDS(g, l) \
  __builtin_amdgcn_global_load_lds((const __attribute__((address_space(1))) void*)(g), \
                                   (__attribute__((address_space(3))) void*)(l), 16, 0, 0)

__global__ void k_init(unsigned* sl) {
  sl[SL_MAXW1] = 0u; sl[SL_MAXW2] = 0u; sl[SL_MAXY] = 0u;
}

// grid-stride absmax of a f32 array -> atomicMax on float bits (non-neg floats order as uints)
__global__ void k_absmax(const float* __restrict__ src, int n, unsigned* slot) {
  float m = 0.f;
  for (int i = blockIdx.x * blockDim.x + threadIdx.x; i < n; i += gridDim.x * blockDim.x)
    m = fmaxf(m, fabsf(src[i]));
  #pragma unroll
  for (int off = 32; off; off >>= 1) m = fmaxf(m, __shfl_down(m, off, 64));
  __shared__ float wm[4];
  int lane = threadIdx.x & 63, wid = threadIdx.x >> 6;
  if (lane == 0) wm[wid] = m;
  __syncthreads();
  if (threadIdx.x == 0) {
    float b = wm[0];
    for (int i = 1; i < (int)(blockDim.x >> 6); i++) b = fmaxf(b, wm[i]);
    atomicMax(slot, __float_as_uint(b));
  }
}

// Mirror the reference's f32 scalar math exactly (op order matters for floor/round).
__global__ void k_scalars1(unsigned* slu, const float* s_x_ptr) {
  float* slf = (float*)slu;
  float s_w1 = __uint_as_float(slu[SL_MAXW1]) / 127.0f;
  float s_w2 = __uint_as_float(slu[SL_MAXW2]) / 127.0f;
  float s1  = s_x_ptr[0] * s_w1;                    // s_out of linear1
  float sfe = s1 / 1.4142f;                         // sf / K_SQRT2
  float berf = floorf(-1.769f / sfe);               // COEF_B / sf
  float cerf = floorf(((float)(1.0 / -0.2888)) / (sfe * sfe)); // COEF_C / sf^2
  float sig  = ((sfe * sfe) * -0.2888f) * 16384.0f; // sf^2*COEF_A * 2^14
  float shiftv = floorf(1.0f / sig);
  float s2 = (s1 * sig) / 2.0f;
  slf[SL_S1] = s1; slf[SL_BERF] = berf; slf[SL_CERF] = cerf;
  slf[SL_SHIFT] = shiftv; slf[SL_S2] = s2; slf[SL_SW1] = s_w1; slf[SL_SW2] = s_w2;
}

__global__ void k_scalars2(unsigned* slu, float* dout_scalar) {
  float* slf = (float*)slu;
  float maxy = __uint_as_float(slu[SL_MAXY]);
  float xm = fabsf(maxy * slf[SL_S2]);   // max |x_hat| (rounding is monotone -> max commutes)
  float sa = xm / 127.0f;
  float sout2 = sa * slf[SL_SW2];
  slf[SL_SA] = sa; slf[SL_SOUT2] = sout2;
  *dout_scalar = sout2;                  // second reference output (scalar s)
}

__global__ void k_quant_w(const float* __restrict__ w, int8_t* __restrict__ wq, int n,
                          const unsigned* __restrict__ slu, int swslot) {
  float sw = ((const float*)slu)[swslot];
  for (int i = blockIdx.x * blockDim.x + threadIdx.x; i < n; i += gridDim.x * blockDim.x) {
    float q = rintf(w[i] / sw);
    q = fminf(fmaxf(q, -127.f), 127.f);
    wq[i] = (int8_t)q;
  }
}

__global__ void k_cvt_x(const int* __restrict__ x, int8_t* __restrict__ xq, int n, int npad) {
  for (int i = blockIdx.x * blockDim.x + threadIdx.x; i < npad; i += gridDim.x * blockDim.x)
    xq[i] = (i < n) ? (int8_t)x[i] : (int8_t)0;
}

// Elementwise requant: y f32 -> q int8 (coalesced, float4 in / char4 out)
__global__ void k_requant(const float* __restrict__ y, int8_t* __restrict__ q,
                          const unsigned* __restrict__ slu, int n4) {
  const float* slf = (const float*)slu;
  float s2 = slf[SL_S2], sa = slf[SL_SA];
  float r = s2 / sa;
  const float4* y4 = (const float4*)y;
  for (int i = blockIdx.x * blockDim.x + threadIdx.x; i < n4; i += gridDim.x * blockDim.x) {
    float4 v = y4[i];
    int qa = (int)fminf(fmaxf(rintf(v.x * r), -128.f), 127.f);
    int qb = (int)fminf(fmaxf(rintf(v.y * r), -128.f), 127.f);
    int qc = (int)fminf(fmaxf(rintf(v.z * r), -128.f), 127.f);
    int qd = (int)fminf(fmaxf(rintf(v.w * r), -128.f), 127.f);
    unsigned packed = (unsigned)(qa & 0xff) | ((unsigned)(qb & 0xff) << 8) |
                      ((unsigned)(qc & 0xff) << 16) | ((unsigned)(qd & 0xff) << 24);
    ((unsigned*)q)[i] = packed;
  }
}

// MODE 0: GEMM1 + IntGELU -> global absmax(y)   (nothing stored; fallback path)
// MODE 1: GEMM1 + IntGELU -> requant -> q int8  (fallback path, scattered stores)
// MODE 2: GEMM2 + bias     -> f32 out
// MODE 3: GEMM1 + IntGELU -> store y f32 + global absmax(y)  (main path)
template <int K, int MODE>
__global__ __launch_bounds__(256) void k_gemm(
    const int8_t* __restrict__ A, const int8_t* __restrict__ Bm,
    const float* __restrict__ bias, const unsigned* __restrict__ slu,
    int8_t* __restrict__ qout, float* __restrict__ fout, unsigned* maxslot,
    int Mreal, int Ncols) {
  __shared__ alignas(16) int8_t As[128 * 64];
  __shared__ alignas(16) int8_t Bs[128 * 64];
  const int t = threadIdx.x;
  const int bm = blockIdx.y, bn = blockIdx.x;
  const int lane = t & 63, wid = t >> 6;
  const int wRow = (wid >> 1) * 64, wCol = (wid & 1) * 64;
  const int lm = lane & 15, lkb = (lane >> 4) * 16;  // A/B frag: m/n = lane&15, k-bytes at quad*16

  v4i acc[4][4] = {};

  const size_t aBase = (size_t)bm * 128 * K;
  const size_t bBase = (size_t)bn * 128 * K;

  for (int k0 = 0; k0 < K; k0 += 64) {
    #pragma unroll
    for (int c = 0; c < 2; c++) {
      int lin = c * 256 + t;          // 0..511 16B chunks; row-major over [128][64]
      int row = lin >> 2;
      int colb = (lin & 3) << 4;
      GLD_LDS(A + aBase + (size_t)row * K + k0 + colb, As + lin * 16);
      GLD_LDS(Bm + bBase + (size_t)row * K + k0 + colb, Bs + lin * 16);
    }
    __syncthreads();
    v4i af[4], bf[4];
    #pragma unroll
    for (int i = 0; i < 4; i++) af[i] = *(const v4i*)(As + (wRow + i * 16 + lm) * 64 + lkb);
    #pragma unroll
    for (int i = 0; i < 4; i++) bf[i] = *(const v4i*)(Bs + (wCol + i * 16 + lm) * 64 + lkb);
    #pragma unroll
    for (int i = 0; i < 4; i++)
      #pragma unroll
      for (int j = 0; j < 4; j++)
        acc[i][j] = __builtin_amdgcn_mfma_i32_16x16x64_i8(af[i], bf[j], acc[i][j], 0, 0, 0);
    __syncthreads();
  }

  const float* slf = (const float*)slu;
  if constexpr (MODE == 2) {
    float sout2 = slf[SL_SOUT2];
    #pragma unroll
    for (int j = 0; j < 4; j++) {
      int gc = bn * 128 + wCol + j * 16 + lm;
      float bint = rintf(bias[gc] / sout2);
      #pragma unroll
      for (int i = 0; i < 4; i++) {
        int r0 = bm * 128 + wRow + i * 16 + (lane >> 4) * 4;  // C/D: row=quad*4+reg, col=lane&15
        #pragma unroll
        for (int r = 0; r < 4; r++) {
          int gr = r0 + r;
          if (gr < Mreal) fout[(size_t)gr * Ncols + gc] = (float)acc[i][j][r] + bint;
        }
      }
    }
  } else {
    float s1 = slf[SL_S1], berf = slf[SL_BERF], cerf = slf[SL_CERF], shiftv = slf[SL_SHIFT];
    float s2 = slf[SL_S2];
    float sa = (MODE == 1) ? slf[SL_SA] : 1.0f;
    float lmax = 0.f;
    #pragma unroll
    for (int j = 0; j < 4; j++) {
      int gc = bn * 128 + wCol + j * 16 + lm;
      float bint = rintf(bias[gc] / s1);
      #pragma unroll
      for (int i = 0; i < 4; i++) {
        int r0 = bm * 128 + wRow + i * 16 + (lane >> 4) * 4;
        #pragma unroll
        for (int r = 0; r < 4; r++) {
          int gr = r0 + r;
          float a = (float)acc[i][j][r] + bint;                 // int accumulate exact (<2^24)
          float sgn = (a > 0.f) ? 1.f : ((a < 0.f) ? -1.f : 0.f);
          float ax = fminf(fabsf(a), -berf);
          float tt = ax + berf;
          float yv = sgn * (tt * tt + cerf);
          yv = floorf(yv * (1.0f / 16384.0f));                  // floor(y / 2^14), exact scale
          float y = a * (yv + shiftv);                          // y_int
          if constexpr (MODE == 0) {
            if (gr < Mreal) lmax = fmaxf(lmax, fabsf(y));
          } else if constexpr (MODE == 3) {
            if (gr < Mreal) {
              lmax = fmaxf(lmax, fabsf(y));
              fout[(size_t)gr * Ncols + gc] = y;
            }
          } else {
            float qf = rintf((y * s2) / sa);
            qf = fminf(fmaxf(qf, -128.f), 127.f);
            qout[(size_t)gr * Ncols + gc] = (int8_t)qf;         // pad rows harmless
          }
        }
      }
    }
    if constexpr (MODE == 0 || MODE == 3) {
      #pragma unroll
      for (int off = 32; off; off >>= 1) lmax = fmaxf(lmax, __shfl_down(lmax, off, 64));
      if (lane == 0) atomicMax(maxslot, __float_as_uint(lmax));
    }
  }
}

extern "C" void kernel_launch(void* const* d_in, const int* in_sizes, int n_in,
                              void* d_out, int out_size, void* d_ws, size_t ws_size,
                              hipStream_t stream) {
  const int*   x   = (const int*)d_in[0];
  const float* s_x = (const float*)d_in[1];
  const float* w1  = (const float*)d_in[2];
  const float* b1  = (const float*)d_in[3];
  const float* w2  = (const float*)d_in[4];
  const float* b2  = (const float*)d_in[5];
  float* out = (float*)d_out;

  char* ws = (char*)d_ws;
  unsigned* slots = (unsigned*)ws;
  int8_t* w1q = (int8_t*)(ws + 256);
  int8_t* w2q = w1q + (size_t)Hh * Dd;
  int8_t* xq  = w2q + (size_t)Dd * Hh;
  int8_t* qbuf = xq + (size_t)Mpad * Dd;
  float*  ybuf = (float*)(qbuf + (size_t)Mpad * Hh);  // 207.6 MB

  const size_t need = 256 + 2 * (size_t)Hh * Dd + (size_t)Mpad * Dd +
                      (size_t)Mpad * Hh + (size_t)Mpad * Hh * sizeof(float);
  const bool big = ws_size >= need;

  k_init<<<1, 1, 0, stream>>>(slots);
  k_absmax<<<256, 256, 0, stream>>>(w1, Hh * Dd, slots + SL_MAXW1);
  k_absmax<<<256, 256, 0, stream>>>(w2, Dd * Hh, slots + SL_MAXW2);
  k_scalars1<<<1, 1, 0, stream>>>(slots, s_x);
  k_quant_w<<<512, 256, 0, stream>>>(w1, w1q, Hh * Dd, slots, SL_SW1);
  k_quant_w<<<512, 256, 0, stream>>>(w2, w2q, Dd * Hh, slots, SL_SW2);
  k_cvt_x<<<512, 256, 0, stream>>>(x, xq, M * Dd, Mpad * Dd);

  dim3 g1(Hh / 128, MT);   // 32 x 99
  if (big) {
    // GEMM1+GELU -> y f32 + global max|y| (single pass)
    k_gemm<Dd, 3><<<g1, 256, 0, stream>>>(xq, w1q, b1, slots, nullptr, ybuf,
                                          slots + SL_MAXY, M, Hh);
    k_scalars2<<<1, 1, 0, stream>>>(slots, out + (size_t)M * Dd);
    // coalesced elementwise requant y -> q  (pad rows get garbage; GEMM2 discards them)
    k_requant<<<1024, 256, 0, stream>>>(ybuf, qbuf, slots, Mpad * Hh / 4);
  } else {
    // fallback: recompute GEMM1 twice (round-1 path)
    k_gemm<Dd, 0><<<g1, 256, 0, stream>>>(xq, w1q, b1, slots, nullptr, nullptr,
                                          slots + SL_MAXY, M, Hh);
    k_scalars2<<<1, 1, 0, stream>>>(slots, out + (size_t)M * Dd);
    k_gemm<Dd, 1><<<g1, 256, 0, stream>>>(xq, w1q, b1, slots, qbuf, nullptr,
                                          nullptr, M, Hh);
  }
  dim3 g2(Dd / 128, MT);   // 8 x 99
  // GEMM2 + bias -> out
  k_gemm<Hh, 2><<<g2, 256, 0, stream>>>(qbuf, w2q, b2, slots, nullptr, out,
                                        nullptr, M, Dd);
}

// Round 3
// 504.314 us; speedup vs baseline: 1.2231x; 1.2231x over previous
//
#include <hip/hip_runtime.h>
#include <cstdint>
#include <cstddef>

// Problem sizes (fixed by the reference)
constexpr int Bb = 64, Ss = 197, Dd = 1024, Hh = 4096;
constexpr int M  = Bb * Ss;            // 12608 tokens
constexpr int MT = (M + 127) / 128;    // 99 M-tiles
constexpr int Mpad = MT * 128;         // 12672 (padded rows)

// scalar slot indices (at base of ws, as u32/f32)
#define SL_MAXW1 0
#define SL_MAXW2 1
#define SL_MAXY  2
#define SL_S1    4
#define SL_BERF  5
#define SL_CERF  6
#define SL_SHIFT 7
#define SL_S2    8
#define SL_SA    9
#define SL_SOUT2 10
#define SL_SW1   11
#define SL_SW2   12

typedef int v4i __attribute__((ext_vector_type(4)));

#define GLD_LDS(g, l) \
  __builtin_amdgcn_global_load_lds((const __attribute__((address_space(1))) void*)(g), \
                                   (__attribute__((address_space(3))) void*)(l), 16, 0, 0)

__global__ void k_init(unsigned* sl) {
  sl[SL_MAXW1] = 0u; sl[SL_MAXW2] = 0u; sl[SL_MAXY] = 0u;
}

// grid-stride absmax of a f32 array (n divisible by 4) -> atomicMax on float bits
__global__ void k_absmax(const float* __restrict__ src, int n4, unsigned* slot) {
  const float4* s4 = (const float4*)src;
  float m = 0.f;
  for (int i = blockIdx.x * blockDim.x + threadIdx.x; i < n4; i += gridDim.x * blockDim.x) {
    float4 v = s4[i];
    m = fmaxf(m, fmaxf(fmaxf(fabsf(v.x), fabsf(v.y)), fmaxf(fabsf(v.z), fabsf(v.w))));
  }
  #pragma unroll
  for (int off = 32; off; off >>= 1) m = fmaxf(m, __shfl_down(m, off, 64));
  __shared__ float wm[4];
  int lane = threadIdx.x & 63, wid = threadIdx.x >> 6;
  if (lane == 0) wm[wid] = m;
  __syncthreads();
  if (threadIdx.x == 0) {
    float b = wm[0];
    for (int i = 1; i < (int)(blockDim.x >> 6); i++) b = fmaxf(b, wm[i]);
    atomicMax(slot, __float_as_uint(b));
  }
}

// Mirror the reference's f32 scalar math exactly (op order matters for floor/round).
__global__ void k_scalars1(unsigned* slu, const float* s_x_ptr) {
  float* slf = (float*)slu;
  float s_w1 = __uint_as_float(slu[SL_MAXW1]) / 127.0f;
  float s_w2 = __uint_as_float(slu[SL_MAXW2]) / 127.0f;
  float s1  = s_x_ptr[0] * s_w1;                    // s_out of linear1
  float sfe = s1 / 1.4142f;                         // sf / K_SQRT2
  float berf = floorf(-1.769f / sfe);               // COEF_B / sf
  float cerf = floorf(((float)(1.0 / -0.2888)) / (sfe * sfe)); // COEF_C / sf^2
  float sig  = ((sfe * sfe) * -0.2888f) * 16384.0f; // sf^2*COEF_A * 2^14
  float shiftv = floorf(1.0f / sig);
  float s2 = (s1 * sig) / 2.0f;
  slf[SL_S1] = s1; slf[SL_BERF] = berf; slf[SL_CERF] = cerf;
  slf[SL_SHIFT] = shiftv; slf[SL_S2] = s2; slf[SL_SW1] = s_w1; slf[SL_SW2] = s_w2;
}

__global__ void k_scalars2(unsigned* slu, float* dout_scalar) {
  float* slf = (float*)slu;
  float maxy = __uint_as_float(slu[SL_MAXY]);
  float xm = fabsf(maxy * slf[SL_S2]);   // max |x_hat| (rounding is monotone -> max commutes)
  float sa = xm / 127.0f;
  float sout2 = sa * slf[SL_SW2];
  slf[SL_SA] = sa; slf[SL_SOUT2] = sout2;
  *dout_scalar = sout2;                  // second reference output (scalar s)
}

// float4 in -> 4 packed int8 out (n divisible by 4)
__global__ void k_quant_w(const float* __restrict__ w, int8_t* __restrict__ wq, int n4,
                          const unsigned* __restrict__ slu, int swslot) {
  float sw = ((const float*)slu)[swslot];
  const float4* w4 = (const float4*)w;
  for (int i = blockIdx.x * blockDim.x + threadIdx.x; i < n4; i += gridDim.x * blockDim.x) {
    float4 v = w4[i];
    int qa = (int)fminf(fmaxf(rintf(v.x / sw), -127.f), 127.f);
    int qb = (int)fminf(fmaxf(rintf(v.y / sw), -127.f), 127.f);
    int qc = (int)fminf(fmaxf(rintf(v.z / sw), -127.f), 127.f);
    int qd = (int)fminf(fmaxf(rintf(v.w / sw), -127.f), 127.f);
    ((unsigned*)wq)[i] = (unsigned)(qa & 0xff) | ((unsigned)(qb & 0xff) << 8) |
                         ((unsigned)(qc & 0xff) << 16) | ((unsigned)(qd & 0xff) << 24);
  }
}

// int32x4 in -> 4 packed int8 out, zero-fill pad region (sizes divisible by 4)
__global__ void k_cvt_x(const int* __restrict__ x, int8_t* __restrict__ xq, int n4, int npad4) {
  const int4* x4 = (const int4*)x;
  for (int i = blockIdx.x * blockDim.x + threadIdx.x; i < npad4; i += gridDim.x * blockDim.x) {
    unsigned p = 0u;
    if (i < n4) {
      int4 v = x4[i];
      p = (unsigned)(v.x & 0xff) | ((unsigned)(v.y & 0xff) << 8) |
          ((unsigned)(v.z & 0xff) << 16) | ((unsigned)(v.w & 0xff) << 24);
    }
    ((unsigned*)xq)[i] = p;
  }
}

// i8 GEMM, 128x128 tile, BK=128, XOR-swizzled LDS (conflict-free ds_read_b128).
// MODE 0: GEMM1 + IntGELU -> global absmax(y)   (nothing stored)
// MODE 1: GEMM1 + IntGELU -> requant -> q int8
// MODE 2: GEMM2 + bias     -> f32 out
template <int K, int MODE>
__global__ __launch_bounds__(256) void k_gemm(
    const int8_t* __restrict__ A, const int8_t* __restrict__ Bm,
    const float* __restrict__ bias, const unsigned* __restrict__ slu,
    int8_t* __restrict__ qout, float* __restrict__ fout, unsigned* maxslot,
    int Mreal, int Ncols) {
  __shared__ alignas(16) int8_t As[128 * 128];
  __shared__ alignas(16) int8_t Bs[128 * 128];
  const int t = threadIdx.x;
  const int bm = blockIdx.y, bn = blockIdx.x;
  const int lane = t & 63, wid = t >> 6;
  const int wRow = (wid >> 1) * 64, wCol = (wid & 1) * 64;
  const int lm = lane & 15, quad = lane >> 4;

  v4i acc[4][4] = {};

  const size_t aBase = (size_t)bm * 128 * K;
  const size_t bBase = (size_t)bn * 128 * K;

  for (int k0 = 0; k0 < K; k0 += 128) {
    #pragma unroll
    for (int c = 0; c < 4; c++) {
      int s = c * 256 + t;                 // LDS chunk slot 0..1023 (16B chunks)
      int row = s >> 3;
      int cb = (s & 7) ^ (row & 7);        // XOR swizzle: global chunk col for this slot
      size_t goff = (size_t)row * K + k0 + cb * 16;
      GLD_LDS(A + aBase + goff, As + s * 16);
      GLD_LDS(Bm + bBase + goff, Bs + s * 16);
    }
    __syncthreads();
    #pragma unroll
    for (int ks = 0; ks < 2; ks++) {       // two k=64 sub-steps
      v4i af[4], bf[4];
      #pragma unroll
      for (int i = 0; i < 4; i++) {
        int r = wRow + i * 16 + lm;
        af[i] = *(const v4i*)(As + r * 128 + (((ks * 4 + quad) ^ (r & 7)) << 4));
      }
      #pragma unroll
      for (int i = 0; i < 4; i++) {
        int r = wCol + i * 16 + lm;
        bf[i] = *(const v4i*)(Bs + r * 128 + (((ks * 4 + quad) ^ (r & 7)) << 4));
      }
      #pragma unroll
      for (int i = 0; i < 4; i++)
        #pragma unroll
        for (int j = 0; j < 4; j++)
          acc[i][j] = __builtin_amdgcn_mfma_i32_16x16x64_i8(af[i], bf[j], acc[i][j], 0, 0, 0);
    }
    __syncthreads();
  }

  const float* slf = (const float*)slu;
  if constexpr (MODE == 2) {
    float sout2 = slf[SL_SOUT2];
    #pragma unroll
    for (int j = 0; j < 4; j++) {
      int gc = bn * 128 + wCol + j * 16 + lm;
      float bint = rintf(bias[gc] / sout2);
      #pragma unroll
      for (int i = 0; i < 4; i++) {
        int r0 = bm * 128 + wRow + i * 16 + quad * 4;  // C/D: row=quad*4+reg, col=lane&15
        #pragma unroll
        for (int r = 0; r < 4; r++) {
          int gr = r0 + r;
          if (gr < Mreal) fout[(size_t)gr * Ncols + gc] = (float)acc[i][j][r] + bint;
        }
      }
    }
  } else {
    float s1 = slf[SL_S1], berf = slf[SL_BERF], cerf = slf[SL_CERF], shiftv = slf[SL_SHIFT];
    float s2 = slf[SL_S2];
    float sa = (MODE == 1) ? slf[SL_SA] : 1.0f;
    float lmax = 0.f;
    #pragma unroll
    for (int j = 0; j < 4; j++) {
      int gc = bn * 128 + wCol + j * 16 + lm;
      float bint = rintf(bias[gc] / s1);
      #pragma unroll
      for (int i = 0; i < 4; i++) {
        int r0 = bm * 128 + wRow + i * 16 + quad * 4;
        #pragma unroll
        for (int r = 0; r < 4; r++) {
          int gr = r0 + r;
          float a = (float)acc[i][j][r] + bint;                 // int accumulate exact (<2^24)
          float sgn = (a > 0.f) ? 1.f : ((a < 0.f) ? -1.f : 0.f);
          float ax = fminf(fabsf(a), -berf);
          float tt = ax + berf;
          float yv = sgn * (tt * tt + cerf);
          yv = floorf(yv * (1.0f / 16384.0f));                  // floor(y / 2^14), exact scale
          float y = a * (yv + shiftv);                          // y_int
          if constexpr (MODE == 0) {
            if (gr < Mreal) lmax = fmaxf(lmax, fabsf(y));
          } else {
            float qf = rintf((y * s2) / sa);
            qf = fminf(fmaxf(qf, -128.f), 127.f);
            qout[(size_t)gr * Ncols + gc] = (int8_t)qf;         // pad rows harmless
          }
        }
      }
    }
    if constexpr (MODE == 0) {
      #pragma unroll
      for (int off = 32; off; off >>= 1) lmax = fmaxf(lmax, __shfl_down(lmax, off, 64));
      if (lane == 0) atomicMax(maxslot, __float_as_uint(lmax));
    }
  }
}

extern "C" void kernel_launch(void* const* d_in, const int* in_sizes, int n_in,
                              void* d_out, int out_size, void* d_ws, size_t ws_size,
                              hipStream_t stream) {
  const int*   x   = (const int*)d_in[0];
  const float* s_x = (const float*)d_in[1];
  const float* w1  = (const float*)d_in[2];
  const float* b1  = (const float*)d_in[3];
  const float* w2  = (const float*)d_in[4];
  const float* b2  = (const float*)d_in[5];
  float* out = (float*)d_out;

  char* ws = (char*)d_ws;
  unsigned* slots = (unsigned*)ws;
  int8_t* w1q = (int8_t*)(ws + 256);
  int8_t* w2q = w1q + (size_t)Hh * Dd;
  int8_t* xq  = w2q + (size_t)Dd * Hh;
  int8_t* qbuf = xq + (size_t)Mpad * Dd;   // total ws use ~73 MB

  k_init<<<1, 1, 0, stream>>>(slots);
  k_absmax<<<512, 256, 0, stream>>>(w1, Hh * Dd / 4, slots + SL_MAXW1);
  k_absmax<<<512, 256, 0, stream>>>(w2, Dd * Hh / 4, slots + SL_MAXW2);
  k_scalars1<<<1, 1, 0, stream>>>(slots, s_x);
  k_quant_w<<<512, 256, 0, stream>>>(w1, w1q, Hh * Dd / 4, slots, SL_SW1);
  k_quant_w<<<512, 256, 0, stream>>>(w2, w2q, Dd * Hh / 4, slots, SL_SW2);
  k_cvt_x<<<512, 256, 0, stream>>>(x, xq, M * Dd / 4, Mpad * Dd / 4);

  dim3 g1(Hh / 128, MT);   // 32 x 99
  // pass 0: GEMM1+GELU -> max|y|
  k_gemm<Dd, 0><<<g1, 256, 0, stream>>>(xq, w1q, b1, slots, nullptr, nullptr,
                                        slots + SL_MAXY, M, Hh);
  k_scalars2<<<1, 1, 0, stream>>>(slots, out + (size_t)M * Dd);
  // pass 1: GEMM1+GELU -> requant -> q
  k_gemm<Dd, 1><<<g1, 256, 0, stream>>>(xq, w1q, b1, slots, qbuf, nullptr,
                                        nullptr, M, Hh);
  dim3 g2(Dd / 128, MT);   // 8 x 99
  // GEMM2 + bias -> out
  k_gemm<Hh, 2><<<g2, 256, 0, stream>>>(qbuf, w2q, b2, slots, nullptr, out,
                                        nullptr, M, Dd);
}

// Round 4
// 427.232 us; speedup vs baseline: 1.4438x; 1.1804x over previous
//
#include <hip/hip_runtime.h>
#include <cstdint>
#include <cstddef>

// Problem sizes (fixed by the reference)
constexpr int Bb = 64, Ss = 197, Dd = 1024, Hh = 4096;
constexpr int M  = Bb * Ss;            // 12608 tokens
constexpr int MT = (M + 127) / 128;    // 99 M-tiles
constexpr int Mpad = MT * 128;         // 12672 (padded rows)
constexpr int NSLOT = 128;             // scattered atomicMax slots

// scalar slot indices (at base of ws, as u32/f32); maxy slots at [16, 16+NSLOT)
#define SL_MAXW1 0
#define SL_MAXW2 1
#define SL_S1    4
#define SL_BERF  5
#define SL_CERF  6
#define SL_SHIFT 7
#define SL_S2    8
#define SL_SA    9
#define SL_SOUT2 10
#define SL_SW1   11
#define SL_SW2   12
#define SL_MAXY0 16

typedef int v4i __attribute__((ext_vector_type(4)));

#define GLD_LDS(g, l) \
  __builtin_amdgcn_global_load_lds((const __attribute__((address_space(1))) void*)(g), \
                                   (__attribute__((address_space(3))) void*)(l), 16, 0, 0)

__global__ void k_init(unsigned* sl) {
  int t = threadIdx.x;
  if (t < 16 + NSLOT) sl[t] = 0u;
}

// grid-stride absmax of a f32 array (n divisible by 4) -> atomicMax on float bits
__global__ void k_absmax(const float* __restrict__ src, int n4, unsigned* slot) {
  const float4* s4 = (const float4*)src;
  float m = 0.f;
  for (int i = blockIdx.x * blockDim.x + threadIdx.x; i < n4; i += gridDim.x * blockDim.x) {
    float4 v = s4[i];
    m = fmaxf(m, fmaxf(fmaxf(fabsf(v.x), fabsf(v.y)), fmaxf(fabsf(v.z), fabsf(v.w))));
  }
  #pragma unroll
  for (int off = 32; off; off >>= 1) m = fmaxf(m, __shfl_down(m, off, 64));
  __shared__ float wm[4];
  int lane = threadIdx.x & 63, wid = threadIdx.x >> 6;
  if (lane == 0) wm[wid] = m;
  __syncthreads();
  if (threadIdx.x == 0) {
    float b = wm[0];
    for (int i = 1; i < (int)(blockDim.x >> 6); i++) b = fmaxf(b, wm[i]);
    atomicMax(slot, __float_as_uint(b));
  }
}

// Mirror the reference's f32 scalar math exactly (op order matters for floor/round).
__global__ void k_scalars1(unsigned* slu, const float* s_x_ptr) {
  float* slf = (float*)slu;
  float s_w1 = __uint_as_float(slu[SL_MAXW1]) / 127.0f;
  float s_w2 = __uint_as_float(slu[SL_MAXW2]) / 127.0f;
  float s1  = s_x_ptr[0] * s_w1;                    // s_out of linear1
  float sfe = s1 / 1.4142f;                         // sf / K_SQRT2
  float berf = floorf(-1.769f / sfe);               // COEF_B / sf
  float cerf = floorf(((float)(1.0 / -0.2888)) / (sfe * sfe)); // COEF_C / sf^2
  float sig  = ((sfe * sfe) * -0.2888f) * 16384.0f; // sf^2*COEF_A * 2^14
  float shiftv = floorf(1.0f / sig);
  float s2 = (s1 * sig) / 2.0f;
  slf[SL_S1] = s1; slf[SL_BERF] = berf; slf[SL_CERF] = cerf;
  slf[SL_SHIFT] = shiftv; slf[SL_S2] = s2; slf[SL_SW1] = s_w1; slf[SL_SW2] = s_w2;
}

__global__ void k_scalars2(unsigned* slu, float* dout_scalar) {
  float* slf = (float*)slu;
  float maxy = 0.f;
  for (int i = 0; i < NSLOT; i++) maxy = fmaxf(maxy, __uint_as_float(slu[SL_MAXY0 + i]));
  float xm = fabsf(maxy * slf[SL_S2]);   // max |x_hat| (rounding is monotone -> max commutes)
  float sa = xm / 127.0f;
  float sout2 = sa * slf[SL_SW2];
  slf[SL_SA] = sa; slf[SL_SOUT2] = sout2;
  *dout_scalar = sout2;                  // second reference output (scalar s)
}

// float4 in -> 4 packed int8 out (n divisible by 4)
__global__ void k_quant_w(const float* __restrict__ w, int8_t* __restrict__ wq, int n4,
                          const unsigned* __restrict__ slu, int swslot) {
  float sw = ((const float*)slu)[swslot];
  const float4* w4 = (const float4*)w;
  for (int i = blockIdx.x * blockDim.x + threadIdx.x; i < n4; i += gridDim.x * blockDim.x) {
    float4 v = w4[i];
    int qa = (int)fminf(fmaxf(rintf(v.x / sw), -127.f), 127.f);
    int qb = (int)fminf(fmaxf(rintf(v.y / sw), -127.f), 127.f);
    int qc = (int)fminf(fmaxf(rintf(v.z / sw), -127.f), 127.f);
    int qd = (int)fminf(fmaxf(rintf(v.w / sw), -127.f), 127.f);
    ((unsigned*)wq)[i] = (unsigned)(qa & 0xff) | ((unsigned)(qb & 0xff) << 8) |
                         ((unsigned)(qc & 0xff) << 16) | ((unsigned)(qd & 0xff) << 24);
  }
}

// int32x4 in -> 4 packed int8 out, zero-fill pad region (sizes divisible by 4)
__global__ void k_cvt_x(const int* __restrict__ x, int8_t* __restrict__ xq, int n4, int npad4) {
  const int4* x4 = (const int4*)x;
  for (int i = blockIdx.x * blockDim.x + threadIdx.x; i < npad4; i += gridDim.x * blockDim.x) {
    unsigned p = 0u;
    if (i < n4) {
      int4 v = x4[i];
      p = (unsigned)(v.x & 0xff) | ((unsigned)(v.y & 0xff) << 8) |
          ((unsigned)(v.z & 0xff) << 16) | ((unsigned)(v.w & 0xff) << 24);
    }
    ((unsigned*)xq)[i] = p;
  }
}

// i8 GEMM, 128x128 tile, BK=128, XOR-swizzled LDS (conflict-free ds_read_b128).
// MFMA called with swapped operands mfma(bf,af): for acc[i][j] the reg index r is a
// COLUMN index: m = wRow+i*16+(lane&15) [fixed per thread], n = wCol+j*16+quad*4+r.
// MODE 0: GEMM1 + IntGELU -> block-reduced absmax(y) -> 1 atomic into 128 slots
// MODE 1: GEMM1 + IntGELU -> requant -> q int8, coalesced via LDS tile
// MODE 2: GEMM2 + bias     -> f32 out, float4 stores
template <int K, int MODE>
__global__ __launch_bounds__(256) void k_gemm(
    const int8_t* __restrict__ A, const int8_t* __restrict__ Bm,
    const float* __restrict__ bias, const unsigned* __restrict__ slu,
    int8_t* __restrict__ qout, float* __restrict__ fout, unsigned* maxslot,
    int Mreal, int Ncols) {
  __shared__ alignas(16) int8_t smem[32768];
  int8_t* As = smem;
  int8_t* Bs = smem + 16384;
  const int t = threadIdx.x;
  const int bm = blockIdx.y, bn = blockIdx.x;
  const int lane = t & 63, wid = t >> 6;
  const int wRow = (wid >> 1) * 64, wCol = (wid & 1) * 64;
  const int lm = lane & 15, quad = lane >> 4;

  v4i acc[4][4] = {};

  const size_t aBase = (size_t)bm * 128 * K;
  const size_t bBase = (size_t)bn * 128 * K;

  for (int k0 = 0; k0 < K; k0 += 128) {
    #pragma unroll
    for (int c = 0; c < 4; c++) {
      int s = c * 256 + t;                 // LDS chunk slot 0..1023 (16B chunks)
      int row = s >> 3;
      int cb = (s & 7) ^ (row & 7);        // XOR swizzle: global chunk col for this slot
      size_t goff = (size_t)row * K + k0 + cb * 16;
      GLD_LDS(A + aBase + goff, As + s * 16);
      GLD_LDS(Bm + bBase + goff, Bs + s * 16);
    }
    __syncthreads();
    #pragma unroll
    for (int ks = 0; ks < 2; ks++) {       // two k=64 sub-steps
      v4i af[4], bf[4];
      #pragma unroll
      for (int i = 0; i < 4; i++) {
        int r = wRow + i * 16 + lm;
        af[i] = *(const v4i*)(As + r * 128 + (((ks * 4 + quad) ^ (r & 7)) << 4));
      }
      #pragma unroll
      for (int i = 0; i < 4; i++) {
        int r = wCol + i * 16 + lm;
        bf[i] = *(const v4i*)(Bs + r * 128 + (((ks * 4 + quad) ^ (r & 7)) << 4));
      }
      #pragma unroll
      for (int i = 0; i < 4; i++)
        #pragma unroll
        for (int j = 0; j < 4; j++)
          acc[i][j] = __builtin_amdgcn_mfma_i32_16x16x64_i8(bf[j], af[i], acc[i][j], 0, 0, 0);
    }
    __syncthreads();
  }

  const float* slf = (const float*)slu;
  if constexpr (MODE == 2) {
    float sout2 = slf[SL_SOUT2];
    #pragma unroll
    for (int i = 0; i < 4; i++) {
      int gr = bm * 128 + wRow + i * 16 + lm;
      if (gr < Mreal) {
        #pragma unroll
        for (int j = 0; j < 4; j++) {
          int gc0 = bn * 128 + wCol + j * 16 + quad * 4;
          float4 bv = *(const float4*)(bias + gc0);
          float4 o;
          o.x = (float)acc[i][j][0] + rintf(bv.x / sout2);
          o.y = (float)acc[i][j][1] + rintf(bv.y / sout2);
          o.z = (float)acc[i][j][2] + rintf(bv.z / sout2);
          o.w = (float)acc[i][j][3] + rintf(bv.w / sout2);
          *(float4*)(fout + (size_t)gr * Ncols + gc0) = o;
        }
      }
    }
  } else {
    float s1 = slf[SL_S1], berf = slf[SL_BERF], cerf = slf[SL_CERF], shiftv = slf[SL_SHIFT];
    float s2 = slf[SL_S2];
    float sa = (MODE == 1) ? slf[SL_SA] : 1.0f;
    float r_req = (MODE == 1) ? (s2 / sa) : 1.0f;
    float lmax = 0.f;
    const int m = wRow + (t & 15) * 1 + 0;  // placeholder to keep structure clear
    (void)m;
    #pragma unroll
    for (int i = 0; i < 4; i++) {
      int mrow = wRow + i * 16 + lm;
      int gr = bm * 128 + mrow;
      bool rowok = gr < Mreal;
      #pragma unroll
      for (int j = 0; j < 4; j++) {
        int n0 = wCol + j * 16 + quad * 4;
        float4 bv = *(const float4*)(bias + bn * 128 + n0);
        unsigned packed = 0u;
        #pragma unroll
        for (int r = 0; r < 4; r++) {
          float bint = rintf(((const float*)&bv)[r] / s1);
          float a = (float)acc[i][j][r] + bint;                 // int accumulate exact (<2^24)
          float sgn = (a > 0.f) ? 1.f : ((a < 0.f) ? -1.f : 0.f);
          float ax = fminf(fabsf(a), -berf);
          float tt = ax + berf;
          float yv = sgn * (tt * tt + cerf);
          yv = floorf(yv * (1.0f / 16384.0f));                  // floor(y / 2^14), exact scale
          float y = a * (yv + shiftv);                          // y_int
          if constexpr (MODE == 0) {
            if (rowok) lmax = fmaxf(lmax, fabsf(y));
          } else {
            float qf = rintf(y * r_req);
            qf = fminf(fmaxf(qf, -128.f), 127.f);
            packed |= ((unsigned)((int)qf & 0xff)) << (8 * r);
          }
        }
        if constexpr (MODE == 1) {
          // LDS tile [128][132] (pad 4 breaks bank aliasing); dword = 4 consecutive cols
          *(unsigned*)(smem + mrow * 132 + n0) = packed;
        }
      }
    }
    if constexpr (MODE == 0) {
      #pragma unroll
      for (int off = 32; off; off >>= 1) lmax = fmaxf(lmax, __shfl_down(lmax, off, 64));
      float* red = (float*)smem;
      if (lane == 0) red[wid] = lmax;
      __syncthreads();
      if (t == 0) {
        float b = fmaxf(fmaxf(red[0], red[1]), fmaxf(red[2], red[3]));
        int slot = (bm * gridDim.x + bn) & (NSLOT - 1);
        atomicMax(maxslot + slot, __float_as_uint(b));
      }
    } else {
      __syncthreads();
      // coalesced store of the 128x128 int8 tile: 4 x 1KB per wave
      #pragma unroll
      for (int c2 = 0; c2 < 4; c2++) {
        int idx = c2 * 256 + t;
        int row = idx >> 3, c16 = (idx & 7) << 4;
        v4i v = *(const v4i*)(smem + row * 132 + c16);
        *(v4i*)(qout + (size_t)(bm * 128 + row) * Ncols + bn * 128 + c16) = v;
      }
    }
  }
}

extern "C" void kernel_launch(void* const* d_in, const int* in_sizes, int n_in,
                              void* d_out, int out_size, void* d_ws, size_t ws_size,
                              hipStream_t stream) {
  const int*   x   = (const int*)d_in[0];
  const float* s_x = (const float*)d_in[1];
  const float* w1  = (const float*)d_in[2];
  const float* b1  = (const float*)d_in[3];
  const float* w2  = (const float*)d_in[4];
  const float* b2  = (const float*)d_in[5];
  float* out = (float*)d_out;

  char* ws = (char*)d_ws;
  unsigned* slots = (unsigned*)ws;
  int8_t* w1q = (int8_t*)(ws + 1024);
  int8_t* w2q = w1q + (size_t)Hh * Dd;
  int8_t* xq  = w2q + (size_t)Dd * Hh;
  int8_t* qbuf = xq + (size_t)Mpad * Dd;   // total ws use ~73 MB

  k_init<<<1, 256, 0, stream>>>(slots);
  k_absmax<<<512, 256, 0, stream>>>(w1, Hh * Dd / 4, slots + SL_MAXW1);
  k_absmax<<<512, 256, 0, stream>>>(w2, Dd * Hh / 4, slots + SL_MAXW2);
  k_scalars1<<<1, 1, 0, stream>>>(slots, s_x);
  k_quant_w<<<512, 256, 0, stream>>>(w1, w1q, Hh * Dd / 4, slots, SL_SW1);
  k_quant_w<<<512, 256, 0, stream>>>(w2, w2q, Dd * Hh / 4, slots, SL_SW2);
  k_cvt_x<<<512, 256, 0, stream>>>(x, xq, M * Dd / 4, Mpad * Dd / 4);

  dim3 g1(Hh / 128, MT);   // 32 x 99
  // pass 0: GEMM1+GELU -> max|y| (1 atomic/block into 128 slots)
  k_gemm<Dd, 0><<<g1, 256, 0, stream>>>(xq, w1q, b1, slots, nullptr, nullptr,
                                        slots + SL_MAXY0, M, Hh);
  k_scalars2<<<1, 1, 0, stream>>>(slots, out + (size_t)M * Dd);
  // pass 1: GEMM1+GELU -> requant -> q (coalesced via LDS tile)
  k_gemm<Dd, 1><<<g1, 256, 0, stream>>>(xq, w1q, b1, slots, qbuf, nullptr,
                                        nullptr, M, Hh);
  dim3 g2(Dd / 128, MT);   // 8 x 99
  // GEMM2 + bias -> out (float4 stores)
  k_gemm<Hh, 2><<<g2, 256, 0, stream>>>(qbuf, w2q, b2, slots, nullptr, out,
                                        nullptr, M, Dd);
}